// Round 4
// baseline (42.674 us; speedup 1.0000x reference)
//
#include <hip/hip_runtime.h>
#include <hip/hip_bf16.h>

#define B_  8
#define NN  2048
#define D_  256
#define T_  1024
#define M1  20   // NUM_MUT + 1 classes
#define CPW 5    // classes per wave (4 waves x 5 = 20)

#define TOK_PER_BLK 4
#define NBLK ((B_ * T_) / TOK_PER_BLK)   // 2048 blocks; 4 waves each -> 8192 waves
#define BLK_PER_B (NBLK / B_)            // 256 blocks per batch row

// ws layout (floats):
//  [16 .. 16+NBLK)          per-block loss partials (mask*losstok, undivided)
//  [16+NBLK .. 16+2*NBLK)   per-block correct partials
//  [16+2*NBLK .. 16+3*NBLK) per-block mask-count partials
#define PL 16
#define PC (16 + NBLK)
#define PM (16 + 2 * NBLK)

__device__ __forceinline__ float dot4(float4 a, float4 b) {
    return a.x * b.x + a.y * b.y + a.z * b.z + a.w * b.w;
}

// Class-split layout (R3 lesson: 2048 waves = 2 waves/SIMD couldn't hide L3
// latency). Block = 4 waves = 4 tokens; wave w computes classes [5w,5w+5) for
// all 4 tokens (16 lanes/token, lane q holds dims [16q,16q+16)). Scores meet
// in LDS; wave w then does token w's softmax. 8192 waves -> 32 waves/CU grid.
__global__ __launch_bounds__(256, 4) void main_kernel(const float* __restrict__ gnn,
                                                      const float* __restrict__ text,
                                                      const float* __restrict__ scale_p,
                                                      const unsigned int* __restrict__ coords_w,
                                                      const unsigned int* __restrict__ mask_w,
                                                      float* __restrict__ ws)
{
    int tid  = threadIdx.x;
    int lane = tid & 63;
    int w    = tid >> 6;    // wave: class group 5w..5w+4; later, softmax token w
    int p    = lane >> 4;   // token subgroup in wave: 0..3
    int q    = lane & 15;   // sublane: dims [16q, 16q+16)

    __shared__ unsigned int s_flags;                 // bit0: int32 coords, bit1: u8 mask
    __shared__ float s_scores[TOK_PER_BLK][M1];
    __shared__ float s_out[3][TOK_PER_BLK];

    // Fused per-block dtype detection (same 768 B scanned by every block ->
    // L2-broadcast-hot). int64 coords -> odd 32-bit words all zero (values
    // 0..2047); u8-bool mask packs 4 ~80%-true bytes/word -> some word > 1.
    if (tid == 0) s_flags = 0u;
    __syncthreads();
    unsigned int det = 0u;
    if (tid < 16) {                       // first 64 mask words (<= 2048-word bound)
        uint4 m = ((const uint4*)mask_w)[tid];
        if ((m.x > 1u) | (m.y > 1u) | (m.z > 1u) | (m.w > 1u)) det = 2u;
    } else if (tid < 48) {                // first 128 coord words (<= 8192-word bound)
        uint4 c = ((const uint4*)coords_w)[tid - 16];
        if (c.y | c.w) det = 1u;
    }
    if (det) atomicOr(&s_flags, det);
    __syncthreads();
    bool coords_i64 = !(s_flags & 1u);
    bool mask_u8    = (s_flags & 2u) != 0u;

    int token = blockIdx.x * TOK_PER_BLK + p;        // all 4 tokens share one b
    int b = token >> 10;
    int t = token & (T_ - 1);

    int idx = coords_i64 ? (int)coords_w[2 * token] : (int)coords_w[token];

    // Gathered GNN row: lane q holds float4s [4q .. 4q+4)
    const float4* g4 = (const float4*)(gnn + ((size_t)b * NN + idx) * D_) + 4 * q;
    float4 g0 = g4[0], g1 = g4[1], g2 = g4[2], g3 = g4[3];

    // 5 class rows per wave; 24 VMEM instrs/wave, hidden by 16+ waves/CU
    const float4* tb = (const float4*)(text + (((size_t)b * M1) * T_ + t) * D_) + 4 * q;
    float s[CPW];
#pragma unroll
    for (int c = 0; c < CPW; ++c) {
        const float4* r = tb + (size_t)(w * CPW + c) * T_ * (D_ / 4);
        float4 t0 = r[0], t1 = r[1], t2 = r[2], t3 = r[3];
        s[c] = dot4(g0, t0) + dot4(g1, t1) + dot4(g2, t2) + dot4(g3, t3);
    }

    // 4-stage butterfly within each 16-lane group
#pragma unroll
    for (int c = 0; c < CPW; ++c) {
        float v = s[c];
        v += __shfl_xor(v, 1, 64);
        v += __shfl_xor(v, 2, 64);
        v += __shfl_xor(v, 4, 64);
        v += __shfl_xor(v, 8, 64);
        s[c] = v;
    }
    if (q == 0) {
#pragma unroll
        for (int c = 0; c < CPW; ++c) s_scores[p][w * CPW + c] = s[c];
    }
    __syncthreads();

    // Softmax: wave w handles token w (all lanes redundant, broadcast LDS reads)
    {
        int tk = blockIdx.x * TOK_PER_BLK + w;
        float scale = scale_p[0];
        float sc[M1];
#pragma unroll
        for (int m = 0; m < M1; ++m) sc[m] = s_scores[w][m] * scale;
        float s0 = sc[0];
        float mx = s0;
#pragma unroll
        for (int m = 1; m < M1; ++m) mx = fmaxf(mx, sc[m]);
        float sum = 0.f;
#pragma unroll
        for (int m = 0; m < M1; ++m) sum += __expf(sc[m] - mx);
        float loss_tok = mx + __logf(sum) - s0;      // lse - s0
        float correct  = (s0 >= mx) ? 1.f : 0.f;     // argmax==0 (first-max rule)
        unsigned int mv = mask_u8 ? (unsigned int)((const unsigned char*)mask_w)[tk]
                                  : mask_w[tk];
        float mk = (mv != 0u) ? 1.f : 0.f;
        if (lane == 0) {
            s_out[0][w] = mk * loss_tok;
            s_out[1][w] = mk * correct;
            s_out[2][w] = mk;
        }
    }
    __syncthreads();
    if (tid == 0) {
        float L = 0.f, C = 0.f, M = 0.f;
#pragma unroll
        for (int i = 0; i < TOK_PER_BLK; ++i) {
            L += s_out[0][i]; C += s_out[1][i]; M += s_out[2][i];
        }
        ws[PL + blockIdx.x] = L;
        ws[PC + blockIdx.x] = C;
        ws[PM + blockIdx.x] = M;
    }
}

// 8 waves; wave b reduces batch-row b's 256 block partials (4 per lane).
__global__ __launch_bounds__(512) void finalize_kernel(const float* __restrict__ ws,
                                                       float* __restrict__ out)
{
    int tid  = threadIdx.x;
    int lane = tid & 63;
    int b    = tid >> 6;   // 0..7

    float l = 0.f, c = 0.f, m = 0.f;
#pragma unroll
    for (int k = 0; k < BLK_PER_B / 64; ++k) {
        int i = b * BLK_PER_B + k * 64 + lane;
        l += ws[PL + i];
        c += ws[PC + i];
        m += ws[PM + i];
    }
#pragma unroll
    for (int d = 1; d < 64; d <<= 1) {
        l += __shfl_xor(l, d, 64);
        c += __shfl_xor(c, d, 64);
        m += __shfl_xor(m, d, 64);
    }

    __shared__ float sl[B_], sc2[B_], sm[B_];
    if (lane == 0) { sl[b] = l / m; sc2[b] = c; sm[b] = m; }
    __syncthreads();
    if (tid == 0) {
        float L = 0.f, C = 0.f, M = 0.f;
#pragma unroll
        for (int i = 0; i < B_; ++i) { L += sl[i]; C += sc2[i]; M += sm[i]; }
        out[0] = L / (float)B_;
        out[1] = C / M;
    }
}

extern "C" void kernel_launch(void* const* d_in, const int* in_sizes, int n_in,
                              void* d_out, int out_size, void* d_ws, size_t ws_size,
                              hipStream_t stream)
{
    const float* gnn           = (const float*)d_in[0];
    const float* text          = (const float*)d_in[1];
    const float* scale         = (const float*)d_in[2];
    const unsigned int* coords = (const unsigned int*)d_in[3];
    const unsigned int* mask   = (const unsigned int*)d_in[4];
    float* ws  = (float*)d_ws;
    float* out = (float*)d_out;

    main_kernel<<<NBLK, 256, 0, stream>>>(gnn, text, scale, coords, mask, ws);
    finalize_kernel<<<1, 512, 0, stream>>>(ws, out);
}

// Round 5
// 34.320 us; speedup vs baseline: 1.2434x; 1.2434x over previous
//
#include <hip/hip_runtime.h>
#include <hip/hip_bf16.h>

#define B_  8
#define NN  2048
#define D_  256
#define T_  1024
#define M1  20   // NUM_MUT + 1 classes

#define TOK_PER_BLK 16
#define NBLK ((B_ * T_) / TOK_PER_BLK)   // 512 main blocks; 4 waves, 4 tokens/wave
#define BLK_PER_B (NBLK / B_)            // 64 blocks per batch row

// ws layout (floats):
//  [16 .. 16+NBLK)          per-block loss partials (mask*losstok, undivided)
//  [16+NBLK .. 16+2*NBLK)   per-block correct partials
//  [16+2*NBLK .. 16+3*NBLK) per-block mask-count partials
#define PL 16
#define PC (16 + NBLK)
#define PM (16 + 2 * NBLK)

__device__ __forceinline__ float dot4(float4 a, float4 b) {
    return a.x * b.x + a.y * b.y + a.z * b.z + a.w * b.w;
}

// R3 tiling (best so far: 16 lanes/token, 4 tokens/wave, 16 tokens/block), with
// the setup kernel replaced by free in-wave dtype detection (2 loads + 2
// ballots, no LDS/barriers — R4 lesson: heavyweight per-block detection +
// class-split LDS exchange regressed 38.7->42.7us; main is fabric-BW-bound at
// ~6.3 TB/s from L3, so only overhead-shaving helps).
__global__ __launch_bounds__(256) void main_kernel(const float* __restrict__ gnn,
                                                   const float* __restrict__ text,
                                                   const float* __restrict__ scale_p,
                                                   const unsigned int* __restrict__ coords_w,
                                                   const unsigned int* __restrict__ mask_w,
                                                   float* __restrict__ ws)
{
    int tid  = threadIdx.x;
    int lane = tid & 63;
    int wid  = tid >> 6;                    // wave in block: 0..3
    int p    = lane >> 4;                   // token subgroup in wave: 0..3
    int q    = lane & 15;                   // sublane within token: 0..15
    int token = blockIdx.x * TOK_PER_BLK + wid * 4 + p;
    int b = token >> 10;
    int t = token & (T_ - 1);

    // Wave-level dtype detection, all-lane-uniform via ballot.
    // Coords: int64 layout -> odd 32-bit words (high halves) all zero (values
    // 0..2047); int32 -> 16 random words all-zero w.p. 2048^-16 ~ 1e-53.
    // Mask: u8-bool packs 4 ~80%-true bytes/word -> some of 64 words > 1
    // (miss prob 0.2^192 ~ 1e-134); int32 words are only 0/1.
    // Bounds: coords >= 8192 words in BOTH layouts (reads idx<=31); mask >=
    // 2048 words in both (reads idx<=63). Same 288 B for every wave -> L2-hot.
    unsigned int cw = (lane < 16) ? coords_w[2 * lane + 1] : 0u;
    bool coords_i64 = (__ballot(cw != 0u) == 0ull);
    bool mask_u8    = (__ballot(mask_w[lane] > 1u) != 0ull);

    int idx = (int)coords_w[coords_i64 ? 2 * token : token];

    // Gathered GNN row: lane q holds float4s [4q .. 4q+4)
    const float4* g4 = (const float4*)(gnn + ((size_t)b * NN + idx) * D_) + 4 * q;
    float4 g0 = g4[0], g1 = g4[1], g2 = g4[2], g3 = g4[3];

    // 20 class rows; 80 independent dwordx4 per lane (addresses independent of
    // the gather chain, so they fill the pipe while idx resolves).
    const float4* tb = (const float4*)(text + (((size_t)b * M1) * T_ + t) * D_) + 4 * q;
    float s[M1];
#pragma unroll
    for (int m = 0; m < M1; ++m) {
        const float4* r = tb + (size_t)m * T_ * (D_ / 4);
        float4 t0 = r[0], t1 = r[1], t2 = r[2], t3 = r[3];
        s[m] = dot4(g0, t0) + dot4(g1, t1) + dot4(g2, t2) + dot4(g3, t3);
    }

    // 4-stage butterfly within each 16-lane group (xor 1,2,4,8 stay in-group)
#pragma unroll
    for (int m = 0; m < M1; ++m) {
        float v = s[m];
        v += __shfl_xor(v, 1, 64);
        v += __shfl_xor(v, 2, 64);
        v += __shfl_xor(v, 4, 64);
        v += __shfl_xor(v, 8, 64);
        s[m] = v;
    }

    float scale = scale_p[0];
    float s0 = s[0] * scale;
    float mx = s0;
#pragma unroll
    for (int m = 1; m < M1; ++m) { s[m] *= scale; mx = fmaxf(mx, s[m]); }
    float sum = __expf(s0 - mx);
#pragma unroll
    for (int m = 1; m < M1; ++m) sum += __expf(s[m] - mx);
    float loss_tok = mx + __logf(sum) - s0;          // lse - s0
    float correct  = (s0 >= mx) ? 1.f : 0.f;         // argmax==0 (first-max rule)

    unsigned int mv = mask_u8 ? (unsigned int)((const unsigned char*)mask_w)[token]
                              : mask_w[token];
    float mk = (mv != 0u) ? 1.f : 0.f;

    // Per-block reduction (16 token groups) -> non-atomic per-block partials
    // (R1 lesson: same-line device atomics serialize at ~40ns each).
    __shared__ float sl[TOK_PER_BLK], sc[TOK_PER_BLK], sm[TOK_PER_BLK];
    if (q == 0) {
        int slot = wid * 4 + p;
        sl[slot] = mk * loss_tok; sc[slot] = mk * correct; sm[slot] = mk;
    }
    __syncthreads();
    if (tid == 0) {
        float L = 0.f, C = 0.f, M = 0.f;
#pragma unroll
        for (int i = 0; i < TOK_PER_BLK; ++i) { L += sl[i]; C += sc[i]; M += sm[i]; }
        ws[PL + blockIdx.x] = L;
        ws[PC + blockIdx.x] = C;
        ws[PM + blockIdx.x] = M;
    }
}

// 8 waves; wave b reduces batch-row b's 64 block partials (1 per lane).
__global__ __launch_bounds__(512) void finalize_kernel(const float* __restrict__ ws,
                                                       float* __restrict__ out)
{
    int tid  = threadIdx.x;
    int lane = tid & 63;
    int b    = tid >> 6;   // 0..7

    int i = b * BLK_PER_B + lane;
    float l = ws[PL + i];
    float c = ws[PC + i];
    float m = ws[PM + i];
#pragma unroll
    for (int d = 1; d < 64; d <<= 1) {
        l += __shfl_xor(l, d, 64);
        c += __shfl_xor(c, d, 64);
        m += __shfl_xor(m, d, 64);
    }

    __shared__ float sl[B_], sc2[B_], sm[B_];
    if (lane == 0) { sl[b] = l / m; sc2[b] = c; sm[b] = m; }
    __syncthreads();
    if (tid == 0) {
        float L = 0.f, C = 0.f, M = 0.f;
#pragma unroll
        for (int i2 = 0; i2 < B_; ++i2) { L += sl[i2]; C += sc2[i2]; M += sm[i2]; }
        out[0] = L / (float)B_;
        out[1] = C / M;
    }
}

extern "C" void kernel_launch(void* const* d_in, const int* in_sizes, int n_in,
                              void* d_out, int out_size, void* d_ws, size_t ws_size,
                              hipStream_t stream)
{
    const float* gnn           = (const float*)d_in[0];
    const float* text          = (const float*)d_in[1];
    const float* scale         = (const float*)d_in[2];
    const unsigned int* coords = (const unsigned int*)d_in[3];
    const unsigned int* mask   = (const unsigned int*)d_in[4];
    float* ws  = (float*)d_ws;
    float* out = (float*)d_out;

    main_kernel<<<NBLK, 256, 0, stream>>>(gnn, text, scale, coords, mask, ws);
    finalize_kernel<<<1, 512, 0, stream>>>(ws, out);
}